// Round 5
// baseline (299.396 us; speedup 1.0000x reference)
//
#include <hip/hip_runtime.h>

#define NGRAPH 64
#define HDIM 128

typedef _Float16 h4 __attribute__((ext_vector_type(4)));
typedef _Float16 h8 __attribute__((ext_vector_type(8)));
typedef float    f4 __attribute__((ext_vector_type(4)));
typedef float    f2 __attribute__((ext_vector_type(2)));

// ---- fused setup + histogram: blocks [0,nb_set) do setup; [nb_set,..) do hist ----
// deg must be zeroed before this kernel (hipMemsetAsync).
__global__ __launch_bounds__(256) void k_setup_hist(const int* __restrict__ bat,
                                                    const int* __restrict__ ei,
                                                    const float* __restrict__ W1,
                                                    const float* __restrict__ W2,
                                                    const float* __restrict__ W3,
                                                    _Float16* __restrict__ Wt,
                                                    int* __restrict__ deg,
                                                    int* __restrict__ rank,
                                                    int* __restrict__ gstart,
                                                    int N, int E, int nb_set) {
  int c = blockIdx.x;
  if (c < nb_set) {
    int i = c * 256 + threadIdx.x;
    if (i < 3 * 16384) {                    // Wt[l][n][k] = fp16(W_l[k][n])
      int l = i >> 14, j = i & 16383;
      int k = j >> 7, n = j & 127;
      const float* W = (l == 0) ? W1 : (l == 1) ? W2 : W3;
      Wt[l * 16384 + n * 128 + k] = (_Float16)W[k * 128 + n];
    }
    if (i < N) {
      int b = bat[i];
      int prev = (i == 0) ? -1 : bat[i - 1];
      for (int g = prev + 1; g <= b; ++g) gstart[g] = i;
      if (i == N - 1)
        for (int g = b + 1; g <= NGRAPH; ++g) gstart[g] = N;
    }
  } else {
    int e = (c - nb_set) * 256 + threadIdx.x;
    if (e < E) rank[e] = atomicAdd(&deg[ei[E + e]], 1);
  }
}

// ---- scan pass 1: per-block exclusive scan of deg ----
__global__ __launch_bounds__(256) void k_scan1(const int* __restrict__ deg,
                                               int* __restrict__ rowptr,
                                               int* __restrict__ bsum, int N) {
  __shared__ int s[256];
  int tid = threadIdx.x;
  int i = blockIdx.x * 256 + tid;
  int v = (i < N) ? deg[i] : 0;
  s[tid] = v;
  __syncthreads();
#pragma unroll
  for (int off = 1; off < 256; off <<= 1) {
    int t = (tid >= off) ? s[tid - off] : 0;
    __syncthreads();
    s[tid] += t;
    __syncthreads();
  }
  if (i < N) rowptr[i] = s[tid] - v;       // block-local exclusive
  if (tid == 255) bsum[blockIdx.x] = s[255];
}

// ---- scan pass 2+3 fused: each block redundantly reduces bsum[0..b); dinv ----
__global__ __launch_bounds__(256) void k_scan23(const int* __restrict__ deg,
                                                int* __restrict__ rowptr,
                                                const int* __restrict__ bsum,
                                                float* __restrict__ dinv,
                                                int N, int E) {
  __shared__ int red[256];
  int b = blockIdx.x, t = threadIdx.x;
  int partial = 0;
  for (int j = t; j < b; j += 256) partial += bsum[j];
  red[t] = partial;
  __syncthreads();
#pragma unroll
  for (int off = 128; off > 0; off >>= 1) {
    if (t < off) red[t] += red[t + off];
    __syncthreads();
  }
  int boff = red[0];
  int i = b * 256 + t;
  if (i < N) {
    rowptr[i] += boff;
    dinv[i] = rsqrtf((float)deg[i] + 1.0f);
  }
  if (i == 0) rowptr[N] = E;
}

// ---- common MFMA compute+store given A-fragments ----
__device__ __forceinline__ void mfma_compute_store(h8 af[2][4],
                                                   const _Float16* ws,
                                                   const float* __restrict__ dinv,
                                                   unsigned char* __restrict__ C,
                                                   int N, int rb, int lm, int q) {
  f4 acc[2][8];
#pragma unroll
  for (int mt = 0; mt < 2; ++mt)
#pragma unroll
    for (int ct = 0; ct < 8; ++ct)
      acc[mt][ct] = (f4){0.0f, 0.0f, 0.0f, 0.0f};

#pragma unroll
  for (int ct = 0; ct < 8; ++ct) {
    h8 bf[4];
#pragma unroll
    for (int kc = 0; kc < 4; ++kc)
      bf[kc] = *(const h8*)&ws[(ct * 16 + lm) * 136 + kc * 32 + q * 8];
#pragma unroll
    for (int mt = 0; mt < 2; ++mt)
#pragma unroll
      for (int kc = 0; kc < 4; ++kc)
        acc[mt][ct] = __builtin_amdgcn_mfma_f32_16x16x32_f16(af[mt][kc], bf[kc],
                                                             acc[mt][ct], 0, 0, 0);
  }

#pragma unroll
  for (int mt = 0; mt < 2; ++mt) {
#pragma unroll
    for (int r = 0; r < 4; ++r) {
      int row = rb + mt * 16 + q * 4 + r;
      if (row < N) {
        float dn = dinv[row];
        unsigned char* Cp = &C[(size_t)row * 128 + lm];
#pragma unroll
        for (int ct = 0; ct < 8; ++ct) {
          float v = acc[mt][ct][r] * dn;
          unsigned int p = __builtin_amdgcn_cvt_pk_fp8_f32(v, v, 0, false);
          Cp[ct * 16] = (unsigned char)(p & 0xFF);
        }
      }
    }
  }
}

__device__ __forceinline__ void stage_w(const _Float16* __restrict__ Wt,
                                        _Float16* ws, int tid) {
#pragma unroll
  for (int i = 0; i < 8; ++i) {
    int c0 = tid + i * 256;
    int r = c0 >> 4;
    int off = (c0 & 15) * 8;
    *(h8*)&ws[r * 136 + off] = *(const h8*)&Wt[r * 128 + off];
  }
  __syncthreads();
}

// ---- MFMA GEMM body, fp16 A (layers 2,3) ----
__device__ __forceinline__ void mfma_body(const _Float16* __restrict__ A,
                                          const _Float16* __restrict__ Wt,
                                          const float* __restrict__ dinv,
                                          unsigned char* __restrict__ C, int N,
                                          int bid, int tid, _Float16* ws) {
  stage_w(Wt, ws, tid);
  const int wv = tid >> 6, l = tid & 63;
  const int lm = l & 15, q = l >> 4;
  const int rb = bid * 128 + wv * 32;

  h8 af[2][4];
#pragma unroll
  for (int mt = 0; mt < 2; ++mt) {
    const _Float16* Ap = &A[(size_t)(rb + mt * 16 + lm) * 128];
#pragma unroll
    for (int kc = 0; kc < 4; ++kc)
      af[mt][kc] = *(const h8*)&Ap[kc * 32 + q * 8];
  }
  mfma_compute_store(af, ws, dinv, C, N, rb, lm, q);
}

// ---- MFMA GEMM body, fp32 A with in-register cvt (layer 1 reads x directly) ----
__device__ __forceinline__ void mfma_body32(const float* __restrict__ A,
                                            const _Float16* __restrict__ Wt,
                                            const float* __restrict__ dinv,
                                            unsigned char* __restrict__ C, int N,
                                            int bid, int tid, _Float16* ws) {
  stage_w(Wt, ws, tid);
  const int wv = tid >> 6, l = tid & 63;
  const int lm = l & 15, q = l >> 4;
  const int rb = bid * 128 + wv * 32;

  h8 af[2][4];
#pragma unroll
  for (int mt = 0; mt < 2; ++mt) {
    int row = rb + mt * 16 + lm;
    if (row < N) {
      const float* Ap = &A[(size_t)row * 128];
#pragma unroll
      for (int kc = 0; kc < 4; ++kc) {
        float4 v0 = *(const float4*)&Ap[kc * 32 + q * 8];
        float4 v1 = *(const float4*)&Ap[kc * 32 + q * 8 + 4];
        h8 a;
        a[0] = (_Float16)v0.x; a[1] = (_Float16)v0.y;
        a[2] = (_Float16)v0.z; a[3] = (_Float16)v0.w;
        a[4] = (_Float16)v1.x; a[5] = (_Float16)v1.y;
        a[6] = (_Float16)v1.z; a[7] = (_Float16)v1.w;
        af[mt][kc] = a;
      }
    } else {
#pragma unroll
      for (int kc = 0; kc < 4; ++kc) {
        h8 a;
#pragma unroll
        for (int j = 0; j < 8; ++j) a[j] = (_Float16)0.0f;
        af[mt][kc] = a;
      }
    }
  }
  mfma_compute_store(af, ws, dinv, C, N, rb, lm, q);
}

// ---- standalone MFMA GEMM (layers 2,3) ----
__global__ __launch_bounds__(256) void k_mfma(const _Float16* __restrict__ A,
                                              const _Float16* __restrict__ Wt,
                                              const float* __restrict__ dinv,
                                              unsigned char* __restrict__ C, int N) {
  __shared__ _Float16 ws[128 * 136];
  mfma_body(A, Wt, dinv, C, N, blockIdx.x, threadIdx.x, ws);
}

// ---- fused: blocks [0,nbg) do mfma layer-1 (fp32 A = x); rest do CSR fill ----
__global__ __launch_bounds__(256) void k_fill_mfma(const float* __restrict__ A32,
                                                   const _Float16* __restrict__ Wt,
                                                   const float* __restrict__ dinv,
                                                   unsigned char* __restrict__ C,
                                                   const int* __restrict__ ei,
                                                   const int* __restrict__ rowptr,
                                                   const int* __restrict__ rank,
                                                   int* __restrict__ col,
                                                   int N, int E, int nbg) {
  __shared__ _Float16 ws[128 * 136];
  if ((int)blockIdx.x < nbg) {
    mfma_body32(A32, Wt, dinv, C, N, blockIdx.x, threadIdx.x, ws);
  } else {
    int e = (blockIdx.x - nbg) * 256 + threadIdx.x;
    if (e < E) {
      int d = ei[E + e];
      col[rowptr[d] + rank[e]] = ei[e];
    }
  }
}

// ---- fp8x16 accumulate: 16 fp8 bytes (uint4) -> 16 fp32 accumulators ----
__device__ __forceinline__ void acc_u4(uint4 w, float* a) {
  f2 t;
  t = __builtin_amdgcn_cvt_pk_f32_fp8((int)w.x, false); a[0]  += t[0]; a[1]  += t[1];
  t = __builtin_amdgcn_cvt_pk_f32_fp8((int)w.x, true ); a[2]  += t[0]; a[3]  += t[1];
  t = __builtin_amdgcn_cvt_pk_f32_fp8((int)w.y, false); a[4]  += t[0]; a[5]  += t[1];
  t = __builtin_amdgcn_cvt_pk_f32_fp8((int)w.y, true ); a[6]  += t[0]; a[7]  += t[1];
  t = __builtin_amdgcn_cvt_pk_f32_fp8((int)w.z, false); a[8]  += t[0]; a[9]  += t[1];
  t = __builtin_amdgcn_cvt_pk_f32_fp8((int)w.z, true ); a[10] += t[0]; a[11] += t[1];
  t = __builtin_amdgcn_cvt_pk_f32_fp8((int)w.w, false); a[12] += t[0]; a[13] += t[1];
  t = __builtin_amdgcn_cvt_pk_f32_fp8((int)w.w, true ); a[14] += t[0]; a[15] += t[1];
}

// ---- gather core: 8 lanes/node, uint4 (16B) loads, unroll-8 -> 128B in
// flight per thread. a[16] accumulates cols [sl*16, sl*16+16). ----
__device__ __forceinline__ void gather_node(const uint4* __restrict__ xw,
                                            const int* __restrict__ col,
                                            int beg, int end, int node, int sl,
                                            float* a) {
  int e = beg;
  for (; e + 7 < end; e += 8) {
    int c0 = col[e],     c1 = col[e + 1], c2 = col[e + 2], c3 = col[e + 3];
    int c4 = col[e + 4], c5 = col[e + 5], c6 = col[e + 6], c7 = col[e + 7];
    uint4 w0 = xw[(size_t)c0 * 8 + sl];
    uint4 w1 = xw[(size_t)c1 * 8 + sl];
    uint4 w2 = xw[(size_t)c2 * 8 + sl];
    uint4 w3 = xw[(size_t)c3 * 8 + sl];
    uint4 w4 = xw[(size_t)c4 * 8 + sl];
    uint4 w5 = xw[(size_t)c5 * 8 + sl];
    uint4 w6 = xw[(size_t)c6 * 8 + sl];
    uint4 w7 = xw[(size_t)c7 * 8 + sl];
    acc_u4(w0, a); acc_u4(w1, a); acc_u4(w2, a); acc_u4(w3, a);
    acc_u4(w4, a); acc_u4(w5, a); acc_u4(w6, a); acc_u4(w7, a);
  }
  for (; e < end; ++e) acc_u4(xw[(size_t)col[e] * 8 + sl], a);
  acc_u4(xw[(size_t)node * 8 + sl], a);    // self-loop row
}

// ---- gather layers 1,2 (fp8 table -> fp16 h): 32 nodes/block, 8 lanes/node ----
__global__ __launch_bounds__(256) void k_gather(const int* __restrict__ rowptr,
                                                const int* __restrict__ col,
                                                const unsigned char* __restrict__ xf8,
                                                const float* __restrict__ dinv,
                                                const float* __restrict__ b,
                                                _Float16* __restrict__ h, int N) {
  int node = blockIdx.x * 32 + (threadIdx.x >> 3);
  if (node >= N) return;
  int sl = threadIdx.x & 7;
  int beg = rowptr[node], end = rowptr[node + 1];
  const uint4* xw = (const uint4*)xf8;     // row = 8 uint4 (128 B)

  float a[16];
#pragma unroll
  for (int j = 0; j < 16; ++j) a[j] = 0.0f;
  gather_node(xw, col, beg, end, node, sl, a);

  float dn = dinv[node];
  const float* bp = &b[sl * 16];
  float4 b0 = *(const float4*)&bp[0];
  float4 b1 = *(const float4*)&bp[4];
  float4 b2 = *(const float4*)&bp[8];
  float4 b3 = *(const float4*)&bp[12];
  h8 o0, o1;
  o0[0] = (_Float16)fmaxf(fmaf(dn, a[0],  b0.x), 0.0f);
  o0[1] = (_Float16)fmaxf(fmaf(dn, a[1],  b0.y), 0.0f);
  o0[2] = (_Float16)fmaxf(fmaf(dn, a[2],  b0.z), 0.0f);
  o0[3] = (_Float16)fmaxf(fmaf(dn, a[3],  b0.w), 0.0f);
  o0[4] = (_Float16)fmaxf(fmaf(dn, a[4],  b1.x), 0.0f);
  o0[5] = (_Float16)fmaxf(fmaf(dn, a[5],  b1.y), 0.0f);
  o0[6] = (_Float16)fmaxf(fmaf(dn, a[6],  b1.z), 0.0f);
  o0[7] = (_Float16)fmaxf(fmaf(dn, a[7],  b1.w), 0.0f);
  o1[0] = (_Float16)fmaxf(fmaf(dn, a[8],  b2.x), 0.0f);
  o1[1] = (_Float16)fmaxf(fmaf(dn, a[9],  b2.y), 0.0f);
  o1[2] = (_Float16)fmaxf(fmaf(dn, a[10], b2.z), 0.0f);
  o1[3] = (_Float16)fmaxf(fmaf(dn, a[11], b2.w), 0.0f);
  o1[4] = (_Float16)fmaxf(fmaf(dn, a[12], b3.x), 0.0f);
  o1[5] = (_Float16)fmaxf(fmaf(dn, a[13], b3.y), 0.0f);
  o1[6] = (_Float16)fmaxf(fmaf(dn, a[14], b3.z), 0.0f);
  o1[7] = (_Float16)fmaxf(fmaf(dn, a[15], b3.w), 0.0f);
  _Float16* hp = &h[(size_t)node * 128 + sl * 16];
  *(h8*)&hp[0] = o0;
  *(h8*)&hp[8] = o1;
}

// ---- fused layer-3 gather + mean-pool: same gather shape (own grid, no GEMM
// sharing), relu'd columns go straight into per-block LDS graph accumulators,
// one guarded global-atomic flush per block. h never touches HBM. ----
__global__ __launch_bounds__(256) void k_gpool(const int* __restrict__ rowptr,
                                               const int* __restrict__ col,
                                               const unsigned char* __restrict__ xf8,
                                               const float* __restrict__ dinv,
                                               const float* __restrict__ b,
                                               const int* __restrict__ bat,
                                               float* __restrict__ gsum, int N) {
  __shared__ float gacc[NGRAPH * 128];
  const int tid = threadIdx.x;
  for (int i = tid; i < NGRAPH * 128; i += 256) gacc[i] = 0.0f;
  __syncthreads();

  int node = blockIdx.x * 32 + (tid >> 3);
  int sl = tid & 7;
  if (node < N) {
    int beg = rowptr[node], end = rowptr[node + 1];
    const uint4* xw = (const uint4*)xf8;
    float a[16];
#pragma unroll
    for (int j = 0; j < 16; ++j) a[j] = 0.0f;
    gather_node(xw, col, beg, end, node, sl, a);

    float dn = dinv[node];
    int g = bat[node];
    const float* bp = &b[sl * 16];
    float* gp = &gacc[g * 128 + sl * 16];
#pragma unroll
    for (int j = 0; j < 16; ++j) {
      float v = fmaxf(fmaf(dn, a[j], bp[j]), 0.0f);
      atomicAdd(&gp[j], v);
    }
  }
  __syncthreads();
  for (int i = tid; i < NGRAPH * 128; i += 256) {
    float v = gacc[i];
    if (v != 0.0f) atomicAdd(&gsum[i], v);
  }
}

// ---- tiny head: out[g] = (gsum[g]/cnt[g]) @ Wc + bc ----
__global__ __launch_bounds__(128) void k_head(const float* __restrict__ gsum,
                                              const int* __restrict__ gstart,
                                              const float* __restrict__ Wc,
                                              const float* __restrict__ bc,
                                              float* __restrict__ out) {
  __shared__ float s[128];
  int g = blockIdx.x, t = threadIdx.x;
  float cnt = (float)(gstart[g + 1] - gstart[g]);
  float inv = 1.0f / fmaxf(cnt, 1.0f);
  s[t] = gsum[g * 128 + t] * inv;
  __syncthreads();
  if (t < 10) {
    float a = 0.0f;
    for (int k = 0; k < 128; ++k)
      a = fmaf(s[k], Wc[k * 10 + t], a);
    out[g * 10 + t] = a + bc[t];
  }
}

extern "C" void kernel_launch(void* const* d_in, const int* in_sizes, int n_in,
                              void* d_out, int out_size, void* d_ws, size_t ws_size,
                              hipStream_t stream) {
  const float* x   = (const float*)d_in[0];
  const int*   ei  = (const int*)d_in[1];
  const int*   bat = (const int*)d_in[2];
  const float* W1  = (const float*)d_in[3];
  const float* b1  = (const float*)d_in[4];
  const float* W2  = (const float*)d_in[5];
  const float* b2  = (const float*)d_in[6];
  const float* W3  = (const float*)d_in[7];
  const float* b3  = (const float*)d_in[8];
  const float* Wc  = (const float*)d_in[9];
  const float* bc  = (const float*)d_in[10];

  const int N = in_sizes[0] / 128;
  const int E = in_sizes[1] / 2;
  const int NP = ((N + 127) / 128) * 128;        // padded rows

  // workspace layout (deg + gsum adjacent -> single memset)
  char* wsb = (char*)d_ws;
  int*   deg    = (int*)wsb;                      wsb += (size_t)N * 4;
  float* gsum   = (float*)wsb;                    wsb += NGRAPH * 128 * 4;
  int*   rowptr = (int*)wsb;                      wsb += (size_t)(N + 1) * 4;
  int*   bsum   = (int*)wsb;                      wsb += 256 * 4;
  float* dinv   = (float*)wsb;                    wsb += (size_t)N * 4;
  int*   col    = (int*)wsb;                      wsb += (size_t)E * 4;
  int*   rank   = (int*)wsb;                      wsb += (size_t)E * 4;
  int*   gstart = (int*)wsb;                      wsb += (NGRAPH + 1) * 4;
  wsb = (char*)(((size_t)wsb + 255) & ~(size_t)255);
  _Float16* Wt  = (_Float16*)wsb;                 wsb += 3 * 16384 * 2;
  wsb = (char*)(((size_t)wsb + 255) & ~(size_t)255);
  unsigned char* B1 = (unsigned char*)wsb;        wsb += (size_t)NP * 128;     // fp8 table
  wsb = (char*)(((size_t)wsb + 255) & ~(size_t)255);
  _Float16* B2  = (_Float16*)wsb;

  const int setup_elems = (N > 3 * 16384) ? N : 3 * 16384;
  const int nb_set = (setup_elems + 255) / 256;
  const int nb_N   = (N + 255) / 256;
  const int nb_E   = (E + 255) / 256;
  const int nb_gem = (N + 127) / 128;
  const int nb_gat = (N + 31) / 32;

  hipMemsetAsync(deg, 0, ((size_t)N + NGRAPH * 128) * 4, stream);
  k_setup_hist<<<nb_set + nb_E, 256, 0, stream>>>(bat, ei, W1, W2, W3,
                                                  Wt, deg, rank, gstart,
                                                  N, E, nb_set);
  k_scan1<<<nb_N, 256, 0, stream>>>(deg, rowptr, bsum, N);
  k_scan23<<<nb_N, 256, 0, stream>>>(deg, rowptr, bsum, dinv, N, E);

  // layer 1 GEMM (fp32 A = x, in-register cvt) overlapped with atomic-free CSR fill
  k_fill_mfma<<<nb_gem + nb_E, 256, 0, stream>>>(x, Wt, dinv, B1,
                                                 ei, rowptr, rank, col, N, E, nb_gem);
  k_gather<<<nb_gat, 256, 0, stream>>>(rowptr, col, B1, dinv, b1, B2, N);

  k_mfma<<<nb_gem, 256, 0, stream>>>(B2, Wt + 16384, dinv, B1, N);
  k_gather<<<nb_gat, 256, 0, stream>>>(rowptr, col, B1, dinv, b2, B2, N);

  k_mfma<<<nb_gem, 256, 0, stream>>>(B2, Wt + 32768, dinv, B1, N);
  // layer 3: gather fused with mean-pool (no h round-trip), then tiny head
  k_gpool<<<nb_gat, 256, 0, stream>>>(rowptr, col, B1, dinv, b3, bat, gsum, N);
  k_head<<<NGRAPH, 128, 0, stream>>>(gsum, gstart, Wc, bc, (float*)d_out);
}

// Round 6
// 248.530 us; speedup vs baseline: 1.2047x; 1.2047x over previous
//
#include <hip/hip_runtime.h>

#define NGRAPH 64
#define HDIM 128

typedef _Float16 h4 __attribute__((ext_vector_type(4)));
typedef _Float16 h8 __attribute__((ext_vector_type(8)));
typedef float    f4 __attribute__((ext_vector_type(4)));
typedef float    f2 __attribute__((ext_vector_type(2)));

// ---- fused setup + histogram: blocks [0,nb_set) do setup; [nb_set,..) do hist ----
// deg must be zeroed before this kernel (hipMemsetAsync).
__global__ __launch_bounds__(256) void k_setup_hist(const int* __restrict__ bat,
                                                    const int* __restrict__ ei,
                                                    const float* __restrict__ W1,
                                                    const float* __restrict__ W2,
                                                    const float* __restrict__ W3,
                                                    _Float16* __restrict__ Wt,
                                                    int* __restrict__ deg,
                                                    int* __restrict__ rank,
                                                    int* __restrict__ gstart,
                                                    int N, int E, int nb_set) {
  int c = blockIdx.x;
  if (c < nb_set) {
    int i = c * 256 + threadIdx.x;
    if (i < 3 * 16384) {                    // Wt[l][n][k] = fp16(W_l[k][n])
      int l = i >> 14, j = i & 16383;
      int k = j >> 7, n = j & 127;
      const float* W = (l == 0) ? W1 : (l == 1) ? W2 : W3;
      Wt[l * 16384 + n * 128 + k] = (_Float16)W[k * 128 + n];
    }
    if (i < N) {
      int b = bat[i];
      int prev = (i == 0) ? -1 : bat[i - 1];
      for (int g = prev + 1; g <= b; ++g) gstart[g] = i;
      if (i == N - 1)
        for (int g = b + 1; g <= NGRAPH; ++g) gstart[g] = N;
    }
  } else {
    int e = (c - nb_set) * 256 + threadIdx.x;
    if (e < E) rank[e] = atomicAdd(&deg[ei[E + e]], 1);
  }
}

// ---- scan pass 1: per-block exclusive scan of deg ----
__global__ __launch_bounds__(256) void k_scan1(const int* __restrict__ deg,
                                               int* __restrict__ rowptr,
                                               int* __restrict__ bsum, int N) {
  __shared__ int s[256];
  int tid = threadIdx.x;
  int i = blockIdx.x * 256 + tid;
  int v = (i < N) ? deg[i] : 0;
  s[tid] = v;
  __syncthreads();
#pragma unroll
  for (int off = 1; off < 256; off <<= 1) {
    int t = (tid >= off) ? s[tid - off] : 0;
    __syncthreads();
    s[tid] += t;
    __syncthreads();
  }
  if (i < N) rowptr[i] = s[tid] - v;       // block-local exclusive
  if (tid == 255) bsum[blockIdx.x] = s[255];
}

// ---- scan pass 2+3 fused: each block redundantly reduces bsum[0..b); dinv ----
__global__ __launch_bounds__(256) void k_scan23(const int* __restrict__ deg,
                                                int* __restrict__ rowptr,
                                                const int* __restrict__ bsum,
                                                float* __restrict__ dinv,
                                                int N, int E) {
  __shared__ int red[256];
  int b = blockIdx.x, t = threadIdx.x;
  int partial = 0;
  for (int j = t; j < b; j += 256) partial += bsum[j];
  red[t] = partial;
  __syncthreads();
#pragma unroll
  for (int off = 128; off > 0; off >>= 1) {
    if (t < off) red[t] += red[t + off];
    __syncthreads();
  }
  int boff = red[0];
  int i = b * 256 + t;
  if (i < N) {
    rowptr[i] += boff;
    dinv[i] = rsqrtf((float)deg[i] + 1.0f);
  }
  if (i == 0) rowptr[N] = E;
}

// ---- common MFMA compute+store given A-fragments ----
__device__ __forceinline__ void mfma_compute_store(h8 af[2][4],
                                                   const _Float16* ws,
                                                   const float* __restrict__ dinv,
                                                   unsigned char* __restrict__ C,
                                                   int N, int rb, int lm, int q) {
  f4 acc[2][8];
#pragma unroll
  for (int mt = 0; mt < 2; ++mt)
#pragma unroll
    for (int ct = 0; ct < 8; ++ct)
      acc[mt][ct] = (f4){0.0f, 0.0f, 0.0f, 0.0f};

#pragma unroll
  for (int ct = 0; ct < 8; ++ct) {
    h8 bf[4];
#pragma unroll
    for (int kc = 0; kc < 4; ++kc)
      bf[kc] = *(const h8*)&ws[(ct * 16 + lm) * 136 + kc * 32 + q * 8];
#pragma unroll
    for (int mt = 0; mt < 2; ++mt)
#pragma unroll
      for (int kc = 0; kc < 4; ++kc)
        acc[mt][ct] = __builtin_amdgcn_mfma_f32_16x16x32_f16(af[mt][kc], bf[kc],
                                                             acc[mt][ct], 0, 0, 0);
  }

#pragma unroll
  for (int mt = 0; mt < 2; ++mt) {
#pragma unroll
    for (int r = 0; r < 4; ++r) {
      int row = rb + mt * 16 + q * 4 + r;
      if (row < N) {
        float dn = dinv[row];
        unsigned char* Cp = &C[(size_t)row * 128 + lm];
#pragma unroll
        for (int ct = 0; ct < 8; ++ct) {
          float v = acc[mt][ct][r] * dn;
          unsigned int p = __builtin_amdgcn_cvt_pk_fp8_f32(v, v, 0, false);
          Cp[ct * 16] = (unsigned char)(p & 0xFF);
        }
      }
    }
  }
}

__device__ __forceinline__ void stage_w(const _Float16* __restrict__ Wt,
                                        _Float16* ws, int tid) {
#pragma unroll
  for (int i = 0; i < 8; ++i) {
    int c0 = tid + i * 256;
    int r = c0 >> 4;
    int off = (c0 & 15) * 8;
    *(h8*)&ws[r * 136 + off] = *(const h8*)&Wt[r * 128 + off];
  }
  __syncthreads();
}

// ---- MFMA GEMM body, fp16 A (layers 2,3) ----
__device__ __forceinline__ void mfma_body(const _Float16* __restrict__ A,
                                          const _Float16* __restrict__ Wt,
                                          const float* __restrict__ dinv,
                                          unsigned char* __restrict__ C, int N,
                                          int bid, int tid, _Float16* ws) {
  stage_w(Wt, ws, tid);
  const int wv = tid >> 6, l = tid & 63;
  const int lm = l & 15, q = l >> 4;
  const int rb = bid * 128 + wv * 32;

  h8 af[2][4];
#pragma unroll
  for (int mt = 0; mt < 2; ++mt) {
    const _Float16* Ap = &A[(size_t)(rb + mt * 16 + lm) * 128];
#pragma unroll
    for (int kc = 0; kc < 4; ++kc)
      af[mt][kc] = *(const h8*)&Ap[kc * 32 + q * 8];
  }
  mfma_compute_store(af, ws, dinv, C, N, rb, lm, q);
}

// ---- MFMA GEMM body, fp32 A with in-register cvt (layer 1 reads x directly) ----
__device__ __forceinline__ void mfma_body32(const float* __restrict__ A,
                                            const _Float16* __restrict__ Wt,
                                            const float* __restrict__ dinv,
                                            unsigned char* __restrict__ C, int N,
                                            int bid, int tid, _Float16* ws) {
  stage_w(Wt, ws, tid);
  const int wv = tid >> 6, l = tid & 63;
  const int lm = l & 15, q = l >> 4;
  const int rb = bid * 128 + wv * 32;

  h8 af[2][4];
#pragma unroll
  for (int mt = 0; mt < 2; ++mt) {
    int row = rb + mt * 16 + lm;
    if (row < N) {
      const float* Ap = &A[(size_t)row * 128];
#pragma unroll
      for (int kc = 0; kc < 4; ++kc) {
        float4 v0 = *(const float4*)&Ap[kc * 32 + q * 8];
        float4 v1 = *(const float4*)&Ap[kc * 32 + q * 8 + 4];
        h8 a;
        a[0] = (_Float16)v0.x; a[1] = (_Float16)v0.y;
        a[2] = (_Float16)v0.z; a[3] = (_Float16)v0.w;
        a[4] = (_Float16)v1.x; a[5] = (_Float16)v1.y;
        a[6] = (_Float16)v1.z; a[7] = (_Float16)v1.w;
        af[mt][kc] = a;
      }
    } else {
#pragma unroll
      for (int kc = 0; kc < 4; ++kc) {
        h8 a;
#pragma unroll
        for (int j = 0; j < 8; ++j) a[j] = (_Float16)0.0f;
        af[mt][kc] = a;
      }
    }
  }
  mfma_compute_store(af, ws, dinv, C, N, rb, lm, q);
}

// ---- standalone MFMA GEMM (layers 2,3) ----
__global__ __launch_bounds__(256) void k_mfma(const _Float16* __restrict__ A,
                                              const _Float16* __restrict__ Wt,
                                              const float* __restrict__ dinv,
                                              unsigned char* __restrict__ C, int N) {
  __shared__ _Float16 ws[128 * 136];
  mfma_body(A, Wt, dinv, C, N, blockIdx.x, threadIdx.x, ws);
}

// ---- fused: blocks [0,nbg) do mfma layer-1 (fp32 A = x); rest do CSR fill ----
__global__ __launch_bounds__(256) void k_fill_mfma(const float* __restrict__ A32,
                                                   const _Float16* __restrict__ Wt,
                                                   const float* __restrict__ dinv,
                                                   unsigned char* __restrict__ C,
                                                   const int* __restrict__ ei,
                                                   const int* __restrict__ rowptr,
                                                   const int* __restrict__ rank,
                                                   int* __restrict__ col,
                                                   int N, int E, int nbg) {
  __shared__ _Float16 ws[128 * 136];
  if ((int)blockIdx.x < nbg) {
    mfma_body32(A32, Wt, dinv, C, N, blockIdx.x, threadIdx.x, ws);
  } else {
    int e = (blockIdx.x - nbg) * 256 + threadIdx.x;
    if (e < E) {
      int d = ei[E + e];
      col[rowptr[d] + rank[e]] = ei[e];
    }
  }
}

// ---- fp8x8 accumulate: 8 fp8 bytes (uint2) -> 8 fp32 accumulators ----
__device__ __forceinline__ void acc_u2(uint2 w, float* a) {
  f2 t;
  t = __builtin_amdgcn_cvt_pk_f32_fp8((int)w.x, false); a[0] += t[0]; a[1] += t[1];
  t = __builtin_amdgcn_cvt_pk_f32_fp8((int)w.x, true ); a[2] += t[0]; a[3] += t[1];
  t = __builtin_amdgcn_cvt_pk_f32_fp8((int)w.y, false); a[4] += t[0]; a[5] += t[1];
  t = __builtin_amdgcn_cvt_pk_f32_fp8((int)w.y, true ); a[6] += t[0]; a[7] += t[1];
}

// ---- gather (fp8 table -> fp16 h): 16 lanes/node (uint2 = 8B/lane), 16
// nodes/block, unroll-8 main loop -> 8 independent loads (64B) in flight per
// thread while staying under the 64-VGPR occupancy step. ----
__global__ __launch_bounds__(256) void k_gather(const int* __restrict__ rowptr,
                                                const int* __restrict__ col,
                                                const unsigned char* __restrict__ xf8,
                                                const float* __restrict__ dinv,
                                                const float* __restrict__ b,
                                                _Float16* __restrict__ h, int N) {
  int node = blockIdx.x * 16 + (threadIdx.x >> 4);
  if (node >= N) return;
  int sl = threadIdx.x & 15;               // lane within node group
  int beg = rowptr[node], end = rowptr[node + 1];
  const uint2* xw = (const uint2*)xf8;     // row stride 16 uint2

  uint2 wsf = xw[(size_t)node * 16 + sl];  // self-loop row, issued early

  float a[8];
#pragma unroll
  for (int j = 0; j < 8; ++j) a[j] = 0.0f;

  int e = beg;
  for (; e + 7 < end; e += 8) {
    int c0 = col[e],     c1 = col[e + 1], c2 = col[e + 2], c3 = col[e + 3];
    int c4 = col[e + 4], c5 = col[e + 5], c6 = col[e + 6], c7 = col[e + 7];
    uint2 w0 = xw[(size_t)c0 * 16 + sl];
    uint2 w1 = xw[(size_t)c1 * 16 + sl];
    uint2 w2 = xw[(size_t)c2 * 16 + sl];
    uint2 w3 = xw[(size_t)c3 * 16 + sl];
    uint2 w4 = xw[(size_t)c4 * 16 + sl];
    uint2 w5 = xw[(size_t)c5 * 16 + sl];
    uint2 w6 = xw[(size_t)c6 * 16 + sl];
    uint2 w7 = xw[(size_t)c7 * 16 + sl];
    acc_u2(w0, a); acc_u2(w1, a); acc_u2(w2, a); acc_u2(w3, a);
    acc_u2(w4, a); acc_u2(w5, a); acc_u2(w6, a); acc_u2(w7, a);
  }
  for (; e + 3 < end; e += 4) {
    int c0 = col[e], c1 = col[e + 1], c2 = col[e + 2], c3 = col[e + 3];
    uint2 w0 = xw[(size_t)c0 * 16 + sl];
    uint2 w1 = xw[(size_t)c1 * 16 + sl];
    uint2 w2 = xw[(size_t)c2 * 16 + sl];
    uint2 w3 = xw[(size_t)c3 * 16 + sl];
    acc_u2(w0, a); acc_u2(w1, a); acc_u2(w2, a); acc_u2(w3, a);
  }
  for (; e < end; ++e) acc_u2(xw[(size_t)col[e] * 16 + sl], a);
  acc_u2(wsf, a);                          // self-loop contribution

  float dn = dinv[node];
  int c = sl * 8;
  float4 b0 = *(const float4*)&b[c];
  float4 b1v = *(const float4*)&b[c + 4];
  h8 o;
  o[0] = (_Float16)fmaxf(fmaf(dn, a[0], b0.x), 0.0f);
  o[1] = (_Float16)fmaxf(fmaf(dn, a[1], b0.y), 0.0f);
  o[2] = (_Float16)fmaxf(fmaf(dn, a[2], b0.z), 0.0f);
  o[3] = (_Float16)fmaxf(fmaf(dn, a[3], b0.w), 0.0f);
  o[4] = (_Float16)fmaxf(fmaf(dn, a[4], b1v.x), 0.0f);
  o[5] = (_Float16)fmaxf(fmaf(dn, a[5], b1v.y), 0.0f);
  o[6] = (_Float16)fmaxf(fmaf(dn, a[6], b1v.z), 0.0f);
  o[7] = (_Float16)fmaxf(fmaf(dn, a[7], b1v.w), 0.0f);
  *(h8*)&h[(size_t)node * 128 + c] = o;
}

// ---- parallel pool stage 1: register-accumulate consecutive nodes (batch is
// sorted so graph boundaries are rare), flush to LDS graph accumulators at
// boundaries, one guarded global-atomic flush per block. ----
__global__ __launch_bounds__(256) void k_psum(const _Float16* __restrict__ h,
                                              const int* __restrict__ bat,
                                              float* __restrict__ gsum, int N) {
  __shared__ float gacc[NGRAPH * 128];
  const int tid = threadIdx.x;
  for (int i = tid; i < NGRAPH * 128; i += 256) gacc[i] = 0.0f;
  __syncthreads();

  const int nrow = tid >> 3;          // 0..31 node slot
  const int sl = tid & 7;             // col octet (16 cols)
  const int base = blockIdx.x * 256;
  float r[16];
#pragma unroll
  for (int j = 0; j < 16; ++j) r[j] = 0.0f;
  int gcur = -1;
#pragma unroll 1
  for (int it = 0; it < 8; ++it) {
    int node = base + it * 32 + nrow;
    if (node >= N) break;
    int g = bat[node];
    if (g != gcur) {
      if (gcur >= 0) {
#pragma unroll
        for (int j = 0; j < 16; ++j) {
          if (r[j] != 0.0f) atomicAdd(&gacc[gcur * 128 + sl * 16 + j], r[j]);
          r[j] = 0.0f;
        }
      }
      gcur = g;
    }
    const _Float16* hp = &h[(size_t)node * 128 + sl * 16];
    h8 x0 = *(const h8*)&hp[0];
    h8 x1 = *(const h8*)&hp[8];
#pragma unroll
    for (int j = 0; j < 8; ++j) { r[j] += (float)x0[j]; r[8 + j] += (float)x1[j]; }
  }
  if (gcur >= 0) {
#pragma unroll
    for (int j = 0; j < 16; ++j)
      if (r[j] != 0.0f) atomicAdd(&gacc[gcur * 128 + sl * 16 + j], r[j]);
  }
  __syncthreads();
  for (int i = tid; i < NGRAPH * 128; i += 256) {
    float v = gacc[i];
    if (v != 0.0f) atomicAdd(&gsum[i], v);
  }
}

// ---- tiny head: out[g] = (gsum[g]/cnt[g]) @ Wc + bc ----
__global__ __launch_bounds__(128) void k_head(const float* __restrict__ gsum,
                                              const int* __restrict__ gstart,
                                              const float* __restrict__ Wc,
                                              const float* __restrict__ bc,
                                              float* __restrict__ out) {
  __shared__ float s[128];
  int g = blockIdx.x, t = threadIdx.x;
  float cnt = (float)(gstart[g + 1] - gstart[g]);
  float inv = 1.0f / fmaxf(cnt, 1.0f);
  s[t] = gsum[g * 128 + t] * inv;
  __syncthreads();
  if (t < 10) {
    float a = 0.0f;
    for (int k = 0; k < 128; ++k)
      a = fmaf(s[k], Wc[k * 10 + t], a);
    out[g * 10 + t] = a + bc[t];
  }
}

extern "C" void kernel_launch(void* const* d_in, const int* in_sizes, int n_in,
                              void* d_out, int out_size, void* d_ws, size_t ws_size,
                              hipStream_t stream) {
  const float* x   = (const float*)d_in[0];
  const int*   ei  = (const int*)d_in[1];
  const int*   bat = (const int*)d_in[2];
  const float* W1  = (const float*)d_in[3];
  const float* b1  = (const float*)d_in[4];
  const float* W2  = (const float*)d_in[5];
  const float* b2  = (const float*)d_in[6];
  const float* W3  = (const float*)d_in[7];
  const float* b3  = (const float*)d_in[8];
  const float* Wc  = (const float*)d_in[9];
  const float* bc  = (const float*)d_in[10];

  const int N = in_sizes[0] / 128;
  const int E = in_sizes[1] / 2;
  const int NP = ((N + 127) / 128) * 128;        // padded rows

  // workspace layout (deg + gsum adjacent -> single memset)
  char* wsb = (char*)d_ws;
  int*   deg    = (int*)wsb;                      wsb += (size_t)N * 4;
  float* gsum   = (float*)wsb;                    wsb += NGRAPH * 128 * 4;
  int*   rowptr = (int*)wsb;                      wsb += (size_t)(N + 1) * 4;
  int*   bsum   = (int*)wsb;                      wsb += 256 * 4;
  float* dinv   = (float*)wsb;                    wsb += (size_t)N * 4;
  int*   col    = (int*)wsb;                      wsb += (size_t)E * 4;
  int*   rank   = (int*)wsb;                      wsb += (size_t)E * 4;
  int*   gstart = (int*)wsb;                      wsb += (NGRAPH + 1) * 4;
  wsb = (char*)(((size_t)wsb + 255) & ~(size_t)255);
  _Float16* Wt  = (_Float16*)wsb;                 wsb += 3 * 16384 * 2;
  wsb = (char*)(((size_t)wsb + 255) & ~(size_t)255);
  unsigned char* B1 = (unsigned char*)wsb;        wsb += (size_t)NP * 128;     // fp8 table
  wsb = (char*)(((size_t)wsb + 255) & ~(size_t)255);
  _Float16* B2  = (_Float16*)wsb;

  const int setup_elems = (N > 3 * 16384) ? N : 3 * 16384;
  const int nb_set = (setup_elems + 255) / 256;
  const int nb_N   = (N + 255) / 256;
  const int nb_E   = (E + 255) / 256;
  const int nb_gem = (N + 127) / 128;
  const int nb_gat = (N + 15) / 16;
  const int nb_ps  = (N + 255) / 256;

  hipMemsetAsync(deg, 0, ((size_t)N + NGRAPH * 128) * 4, stream);
  k_setup_hist<<<nb_set + nb_E, 256, 0, stream>>>(bat, ei, W1, W2, W3,
                                                  Wt, deg, rank, gstart,
                                                  N, E, nb_set);
  k_scan1<<<nb_N, 256, 0, stream>>>(deg, rowptr, bsum, N);
  k_scan23<<<nb_N, 256, 0, stream>>>(deg, rowptr, bsum, dinv, N, E);

  // layer 1 GEMM (fp32 A = x, in-register cvt) overlapped with atomic-free CSR fill
  k_fill_mfma<<<nb_gem + nb_E, 256, 0, stream>>>(x, Wt, dinv, B1,
                                                 ei, rowptr, rank, col, N, E, nb_gem);
  k_gather<<<nb_gat, 256, 0, stream>>>(rowptr, col, B1, dinv, b1, B2, N);

  k_mfma<<<nb_gem, 256, 0, stream>>>(B2, Wt + 16384, dinv, B1, N);
  k_gather<<<nb_gat, 256, 0, stream>>>(rowptr, col, B1, dinv, b2, B2, N);

  k_mfma<<<nb_gem, 256, 0, stream>>>(B2, Wt + 32768, dinv, B1, N);
  k_gather<<<nb_gat, 256, 0, stream>>>(rowptr, col, B1, dinv, b3, B2, N);

  // parallel pool (stage 1) + tiny head
  k_psum<<<nb_ps, 256, 0, stream>>>(B2, bat, gsum, N);
  k_head<<<NGRAPH, 128, 0, stream>>>(gsum, gstart, Wc, bc, (float*)d_out);
}